// Round 1
// 262.239 us; speedup vs baseline: 1.0091x; 1.0091x over previous
//
#include <hip/hip_runtime.h>
#include <hip/hip_bf16.h>
#include <math.h>

// Problem constants
#define Bc 2
#define Tc 2048
#define Cc 1024
#define Hc 16
#define Dc 64
// SCALE = 1/8, GAMMA = 8

typedef __attribute__((ext_vector_type(8))) short short8;   // 8 bf16 (4 VGPRs)
typedef __attribute__((ext_vector_type(4))) float f32x4;    // MFMA C/D frag

#define L2E 1.44269504088896f
#define SM_M 20.0f   // fixed softmax shift; |scores| << 20 (std ~0.3)

__device__ __forceinline__ short f2bf(float x) {
    unsigned u = __float_as_uint(x);
    u += 0x7fff + ((u >> 16) & 1);      // RNE
    return (short)(u >> 16);
}
// pack two non-negative floats to bf16 pair (round-half-up) in 3 VALU ops
__device__ __forceinline__ unsigned pack2bf_fast(float a, float b) {
    unsigned ua = __float_as_uint(a) + 0x8000u;
    unsigned ub = __float_as_uint(b) + 0x8000u;
    return __builtin_amdgcn_perm(ub, ua, 0x07060302);  // (ua>>16)|(ub&0xffff0000)
}
// fast softplus: 2 HW transcendentals, ~1e-6 rel err (invisible at bf16)
__device__ __forceinline__ float softplus_fast(float a) {
    return fmaxf(a, 0.f) + __logf(1.f + __expf(-fabsf(a)));
}

// ---------------------------------------------------------------------------
// bf16 MFMA GEMM (m97 recipe): C[M,N] = A[M,K] @ Bt[N,K]^T
// EPI 0: f32 out. EPI 1: bf16 out. EPI 2: fused moire-QK epilogue.
// EPI 2 requires the Bqk row layout from wtrans_qk below: each wave's 64
// cols = [amp(h, d0..d0+31) | phase(h, d0..d0+31)], so n-tiles 0,1 are amp
// and 2,3 the matching phase IN THE SAME LANE -> no shuffle, and q2/k2
// stores are 16-lane-contiguous 32B runs (R5 post-mortem: scattered 2B
// epilogue stores caused 60x HBM write amplification; this layout avoids it).
// ---------------------------------------------------------------------------
template <int EPI>
__global__ __launch_bounds__(256) void gemm_bt_mfma(
    const short* __restrict__ A, const short* __restrict__ Bt,
    float* __restrict__ Cf, short* __restrict__ Cb, short* __restrict__ Cb2,
    int M, int N, int K)
{
    __shared__ __attribute__((aligned(16))) short As[128 * 32];
    __shared__ __attribute__((aligned(16))) short Bs[128 * 32];

    const int tid = threadIdx.x;
    const int wave = tid >> 6, lane = tid & 63;
    const int quad = lane >> 4, c = lane & 15;
    const int wm = wave >> 1, wn = wave & 1;
    const int m0 = blockIdx.y * 128, n0 = blockIdx.x * 128;

    const int srow = lane >> 2;
    const int scol = (lane & 3) * 8;
    const short* Ag = A  + (size_t)(m0 + wave * 32 + srow) * K + scol;
    const short* Bg = Bt + (size_t)(n0 + wave * 32 + srow) * K + scol;
    short* AsW = As + (wave * 32) * 32;
    short* BsW = Bs + (wave * 32) * 32;

    f32x4 acc[4][4];
#pragma unroll
    for (int i = 0; i < 4; ++i)
#pragma unroll
        for (int j = 0; j < 4; ++j)
            acc[i][j] = (f32x4){0.f, 0.f, 0.f, 0.f};

    for (int k0 = 0; k0 < K; k0 += 32) {
        __syncthreads();
#pragma unroll
        for (int i = 0; i < 2; ++i) {
            __builtin_amdgcn_global_load_lds(
                (const __attribute__((address_space(1))) void*)(Ag + k0 + (size_t)i * 16 * K),
                (__attribute__((address_space(3))) void*)(AsW + i * 16 * 32), 16, 0, 0);
            __builtin_amdgcn_global_load_lds(
                (const __attribute__((address_space(1))) void*)(Bg + k0 + (size_t)i * 16 * K),
                (__attribute__((address_space(3))) void*)(BsW + i * 16 * 32), 16, 0, 0);
        }
        __syncthreads();

        short8 af[4], bf[4];
#pragma unroll
        for (int mt = 0; mt < 4; ++mt)
            af[mt] = *(const short8*)&As[(wm * 64 + mt * 16 + c) * 32 + quad * 8];
#pragma unroll
        for (int nt = 0; nt < 4; ++nt)
            bf[nt] = *(const short8*)&Bs[(wn * 64 + nt * 16 + c) * 32 + quad * 8];
#pragma unroll
        for (int mt = 0; mt < 4; ++mt)
#pragma unroll
            for (int nt = 0; nt < 4; ++nt)
                acc[mt][nt] = __builtin_amdgcn_mfma_f32_16x16x32_bf16(
                    af[mt], bf[nt], acc[mt][nt], 0, 0, 0);
    }

    if (EPI == 2) {
        const int g = n0 >> 7;                 // 0..31
        const int isK = g >> 4;
        const int h = g & 15;
        const float scl = isK ? 1.f : 0.125f;
        short* dst = isK ? Cb2 : Cb;           // k2 : q2, (B,H,T,128)
#pragma unroll
        for (int mt = 0; mt < 4; ++mt) {
#pragma unroll
            for (int reg = 0; reg < 4; ++reg) {
                int m = m0 + wm * 64 + mt * 16 + quad * 4 + reg;
                int bb = m >> 11, tt = m & (Tc - 1);
                size_t base = (((size_t)bb * Hc + h) * Tc + tt) * 128;
#pragma unroll
                for (int nt = 0; nt < 2; ++nt) {
                    float amp = acc[mt][nt][reg];
                    float ph  = acc[mt][nt + 2][reg];
                    int d = wn * 32 + nt * 16 + c;
                    float sp = softplus_fast(amp) * scl;
                    float sn, cs;
                    __sincosf(ph, &sn, &cs);
                    dst[base + d]      = f2bf(sp * cs);
                    dst[base + d + 64] = f2bf(sp * sn);
                }
            }
        }
    } else {
#pragma unroll
        for (int mt = 0; mt < 4; ++mt) {
#pragma unroll
            for (int reg = 0; reg < 4; ++reg) {
                size_t row = m0 + wm * 64 + mt * 16 + quad * 4 + reg;
#pragma unroll
                for (int nt = 0; nt < 4; ++nt) {
                    size_t col = n0 + wn * 64 + nt * 16 + c;
                    if (EPI == 1) Cb[row * N + col] = f2bf(acc[mt][nt][reg]);
                    else          Cf[row * N + col] = acc[mt][nt][reg];
                }
            }
        }
    }
}

// ---------------------------------------------------------------------------
// V projection fused with head-transpose: v2t[(b,h,d),t] = (xb @ Wvt^T).
// Same m97 main loop; epilogue round-trips the 128x128 tile through LDS
// (pitch 136) and stores 4x256B-contiguous runs per instruction (full
// sectors -- respects the R5 write-amplification rule). M=4096,N=K=1024.
// ---------------------------------------------------------------------------
__global__ __launch_bounds__(256) void gemm_v2t(
    const short* __restrict__ A, const short* __restrict__ Bt,
    short* __restrict__ v2t)
{
    __shared__ __attribute__((aligned(16))) short As[128 * 32];
    __shared__ __attribute__((aligned(16))) short Bs[128 * 32];
    __shared__ __attribute__((aligned(16))) short tile[128 * 136];  // [n][t]

    const int K = Cc;
    const int tid = threadIdx.x;
    const int wave = tid >> 6, lane = tid & 63;
    const int quad = lane >> 4, c = lane & 15;
    const int wm = wave >> 1, wn = wave & 1;
    const int m0 = blockIdx.y * 128, n0 = blockIdx.x * 128;

    const int srow = lane >> 2;
    const int scol = (lane & 3) * 8;
    const short* Ag = A  + (size_t)(m0 + wave * 32 + srow) * K + scol;
    const short* Bg = Bt + (size_t)(n0 + wave * 32 + srow) * K + scol;
    short* AsW = As + (wave * 32) * 32;
    short* BsW = Bs + (wave * 32) * 32;

    f32x4 acc[4][4];
#pragma unroll
    for (int i = 0; i < 4; ++i)
#pragma unroll
        for (int j = 0; j < 4; ++j)
            acc[i][j] = (f32x4){0.f, 0.f, 0.f, 0.f};

    for (int k0 = 0; k0 < K; k0 += 32) {
        __syncthreads();
#pragma unroll
        for (int i = 0; i < 2; ++i) {
            __builtin_amdgcn_global_load_lds(
                (const __attribute__((address_space(1))) void*)(Ag + k0 + (size_t)i * 16 * K),
                (__attribute__((address_space(3))) void*)(AsW + i * 16 * 32), 16, 0, 0);
            __builtin_amdgcn_global_load_lds(
                (const __attribute__((address_space(1))) void*)(Bg + k0 + (size_t)i * 16 * K),
                (__attribute__((address_space(3))) void*)(BsW + i * 16 * 32), 16, 0, 0);
        }
        __syncthreads();

        short8 af[4], bf[4];
#pragma unroll
        for (int mt = 0; mt < 4; ++mt)
            af[mt] = *(const short8*)&As[(wm * 64 + mt * 16 + c) * 32 + quad * 8];
#pragma unroll
        for (int nt = 0; nt < 4; ++nt)
            bf[nt] = *(const short8*)&Bs[(wn * 64 + nt * 16 + c) * 32 + quad * 8];
#pragma unroll
        for (int mt = 0; mt < 4; ++mt)
#pragma unroll
            for (int nt = 0; nt < 4; ++nt)
                acc[mt][nt] = __builtin_amdgcn_mfma_f32_16x16x32_bf16(
                    af[mt], bf[nt], acc[mt][nt], 0, 0, 0);
    }

    // epilogue: stash transposed into LDS [n][t]
#pragma unroll
    for (int mt = 0; mt < 4; ++mt)
#pragma unroll
        for (int reg = 0; reg < 4; ++reg) {
            int tl = wm * 64 + mt * 16 + quad * 4 + reg;
#pragma unroll
            for (int nt = 0; nt < 4; ++nt)
                tile[(wn * 64 + nt * 16 + c) * 136 + tl] = f2bf(acc[mt][nt][reg]);
        }
    __syncthreads();

    const int b = m0 >> 11, tl0 = m0 & (Tc - 1);
#pragma unroll
    for (int i = 0; i < 8; ++i) {
        int n = i * 16 + (tid >> 4);
        int t8 = (tid & 15) * 8;
        int ng = n0 + n, h = ng >> 6, d = ng & 63;
        *(short8*)&v2t[(((size_t)b * Hc + h) * Dc + d) * Tc + tl0 + t8] =
            *(const short8*)&tile[n * 136 + t8];
    }
}

// ---------------------------------------------------------------------------
__global__ __launch_bounds__(256) void xconv(const float* __restrict__ x,
                                             short* __restrict__ xb)
{
    int idx = blockIdx.x * 256 + threadIdx.x;
    float4 v = *(const float4*)&x[(size_t)idx * 4];
    short4 o = {f2bf(v.x), f2bf(v.y), f2bf(v.z), f2bf(v.w)};
    *(short4*)&xb[(size_t)idx * 4] = o;
}

// ---------------------------------------------------------------------------
// Wq|Wk transpose-convert with the EPI=2 row permutation.
// Source col ng (0..2047) of half z: sub = ng>>10 (amp/ph), h = (ng>>6)&15,
// d = ng&63. Dest row r = (z*16+h)*128 + (d>>5)*64 + sub*32 + (d&31).
// ---------------------------------------------------------------------------
__global__ __launch_bounds__(256) void wtrans_qk(const float* __restrict__ Wq,
                                                 const float* __restrict__ Wk,
                                                 short* __restrict__ Bt)
{
    __shared__ short tile[64][80];
    const int n0 = blockIdx.x * 64, k0 = blockIdx.y * 64;
    const int half = blockIdx.z;
    const float* W = half ? Wk : Wq;
    const int tid = threadIdx.x;
#pragma unroll
    for (int i = 0; i < 4; ++i) {
        int e = i * 256 + tid;
        int k = e >> 4, n4 = (e & 15) * 4;
        float4 v = *(const float4*)&W[(size_t)(k0 + k) * 2048 + n0 + n4];
        tile[k][n4]     = f2bf(v.x);
        tile[k][n4 + 1] = f2bf(v.y);
        tile[k][n4 + 2] = f2bf(v.z);
        tile[k][n4 + 3] = f2bf(v.w);
    }
    __syncthreads();
#pragma unroll
    for (int i = 0; i < 16; ++i) {
        int e = i * 256 + tid;
        int n = e >> 6, k = e & 63;
        int ng = n0 + n;
        int sub = ng >> 10, hh = (ng >> 6) & 15, dd = ng & 63;
        int r = (half * 16 + hh) * 128 + (dd >> 5) * 64 + sub * 32 + (dd & 31);
        Bt[(size_t)r * Cc + k0 + k] = tile[k][n];
    }
}

// ---------------------------------------------------------------------------
__global__ __launch_bounds__(256) void wtrans2(const float* __restrict__ Wv,
                                               const float* __restrict__ Wo,
                                               short* __restrict__ WtBase)
{
    __shared__ short tile[64][80];
    const int n0 = blockIdx.x * 64, k0 = blockIdx.y * 64;
    const float* W = blockIdx.z ? Wo : Wv;
    short* Wt = WtBase + (size_t)blockIdx.z * Cc * Cc;
    const int tid = threadIdx.x;
#pragma unroll
    for (int i = 0; i < 4; ++i) {
        int e = i * 256 + tid;
        int k = e >> 4, n4 = (e & 15) * 4;
        float4 v = *(const float4*)&W[(size_t)(k0 + k) * Cc + n0 + n4];
        tile[k][n4]     = f2bf(v.x);
        tile[k][n4 + 1] = f2bf(v.y);
        tile[k][n4 + 2] = f2bf(v.z);
        tile[k][n4 + 3] = f2bf(v.w);
    }
    __syncthreads();
#pragma unroll
    for (int i = 0; i < 16; ++i) {
        int e = i * 256 + tid;
        int n = e >> 6, k = e & 63;
        Wt[(size_t)(n0 + n) * Cc + k0 + k] = tile[k][n];
    }
}

// ---------------------------------------------------------------------------
// MFMA flash attention v6: one-tile-deep software pipeline.
// At iteration jt: S(jt) MFMA + softmax + Ps write run alongside the
// INDEPENDENT PV(jt-1) (pf from Ps written last iter, vf from Vt[(jt-1)&1]).
// K staged one tile ahead (jt+1), V staged at jt (one behind K) so the V
// buffer read by PV(jt-1) is never the one being filled. Ps stays single-
// buffered: PV's Ps reads are issued before softmax's Ps writes in program
// order; per-wave LDS ops are processed in order, so WAR is safe without a
// barrier. Epilogue barrier + PV drains the last tile for qx == jtEnd.
// LDS unchanged at 64 KB -> 2 blocks/CU.
// ---------------------------------------------------------------------------
__global__ __launch_bounds__(512, 4) void moire_attn6(
    const short* __restrict__ q2, const short* __restrict__ k2,
    const short* __restrict__ v2t, const float* __restrict__ theta,
    short* __restrict__ att)
{
    __shared__ __attribute__((aligned(16))) short Ks[2][64 * 128];  // 32 KB
    __shared__ __attribute__((aligned(16))) short Vt[2][64 * 64];   // 16 KB
    __shared__ __attribute__((aligned(16))) short Ps[8][16 * 64];   // 16 KB

    const int tid = threadIdx.x;
    const int wave = tid >> 6, lane = tid & 63;
    const int quad = lane >> 4, c = lane & 15;
    const int tx = wave >> 2, wq = wave & 3;
    const int p = blockIdx.x, h = blockIdx.y, b = blockIdx.z;
    const int qx = tx ? (31 - p) : p;    // this wave's q-tile
    const int q0 = qx * 64;
    const float th = theta[h];

    const short* k2b = k2 + (size_t)(b * Hc + h) * Tc * 128;
    const short* v2b = v2t + (size_t)(b * Hc + h) * Dc * Tc;

    // Q B-frags (n = t): row q0 + wq*16 + c, 4 K-chunks of 32
    short8 qf[4];
    const short* qp = q2 + ((size_t)(b * Hc + h) * Tc + q0 + wq * 16 + c) * 128;
#pragma unroll
    for (int i = 0; i < 4; ++i)
        qf[i] = *(const short8*)(qp + i * 32 + quad * 8);

    // gate*L2E = cb*cOff - sb*sOff, base (cb,sb) = angle th/8*(jt*64 - q0 - t_l)
    const int t_l = wq * 16 + c;
    float x0 = th * 0.125f * (float)(q0 + t_l);
    float cb = __cosf(x0), sb = -__sinf(x0);
    float cOff[4][4], sOff[4][4];
#pragma unroll
    for (int mt = 0; mt < 4; ++mt)
#pragma unroll
        for (int reg = 0; reg < 4; ++reg) {
            float a = th * 0.125f * (float)(mt * 16 + quad * 4 + reg);
            cOff[mt][reg] = __cosf(a) * L2E;
            sOff[mt][reg] = __sinf(a) * L2E;
        }
    const float cD = __cosf(8.f * th), sD = __sinf(8.f * th);  // 64-step rotation

    f32x4 oacc[4];
    float lsum = 0.f;
#pragma unroll
    for (int nt = 0; nt < 4; ++nt)
        oacc[nt] = (f32x4){0.f, 0.f, 0.f, 0.f};

    auto stageK = [&](int jts) {
        short* KsB = &Ks[jts & 1][0];
        const int s0 = jts * 64;
#pragma unroll
        for (int i = 0; i < 2; ++i) {          // Ks: 1024 16B chunks
            int ch = i * 512 + tid;
            int row = ch >> 4, j = ch & 15;
            const short* src = k2b + (size_t)(s0 + row) * 128 + ((j ^ (row & 15)) << 3);
            __builtin_amdgcn_global_load_lds(
                (const __attribute__((address_space(1))) void*)src,
                (__attribute__((address_space(3))) void*)(KsB + (i * 512 + wave * 64) * 8),
                16, 0, 0);
        }
    };
    auto stageV = [&](int jts) {
        short* VtB = &Vt[jts & 1][0];
        const int s0 = jts * 64;
        int row = tid >> 3, j = tid & 7;       // Vt: 512 16B chunks
        const short* src = v2b + (size_t)row * Tc + s0 + ((j ^ (row & 7)) << 3);
        __builtin_amdgcn_global_load_lds(
            (const __attribute__((address_space(1))) void*)src,
            (__attribute__((address_space(3))) void*)(VtB + (wave * 64) * 8),
            16, 0, 0);
    };

    // PV for tile jprev: pf from own wave's Ps row (written at iter jprev),
    // vf from Vt[jprev&1].
    auto do_pv = [&](int jprev) {
        const short* VtB = &Vt[jprev & 1][0];
        short8 pf[2];
#pragma unroll
        for (int kk = 0; kk < 2; ++kk)
            pf[kk] = *(const short8*)&Ps[wave][c * 64 +
                         (((kk * 4 + quad) ^ (c & 7)) << 3)];
#pragma unroll
        for (int nt = 0; nt < 4; ++nt)
#pragma unroll
            for (int kk = 0; kk < 2; ++kk) {
                short8 vf = *(const short8*)&VtB[(nt * 16 + c) * 64 +
                             (((kk * 4 + quad) ^ (c & 7)) << 3)];
                oacc[nt] = __builtin_amdgcn_mfma_f32_16x16x32_bf16(
                    pf[kk], vf, oacc[nt], 0, 0, 0);
            }
    };

    // S^T + softmax + Ps write for tile jt; advances the gate base angle.
    auto do_s = [&](int jt) {
        const short* KsB = &Ks[jt & 1][0];
        const bool diag = (jt == qx);

        // S^T = K Q^T : kf A-operand (m=s), qf B-operand (n=t)
        f32x4 s_acc[4];
#pragma unroll
        for (int mt = 0; mt < 4; ++mt) {
            f32x4 a = {0.f, 0.f, 0.f, 0.f};
#pragma unroll
            for (int kk = 0; kk < 4; ++kk) {
                short8 kf = *(const short8*)&KsB[(mt * 16 + c) * 128 +
                                                 (((kk * 4 + quad) ^ c) << 3)];
                a = __builtin_amdgcn_mfma_f32_16x16x32_bf16(kf, qf[kk], a, 0, 0, 0);
            }
            s_acc[mt] = a;
        }

        // p = exp2(s*gate*L2E - M*L2E); fixed shift M (exact softmax)
#pragma unroll
        for (int mt = 0; mt < 4; ++mt) {
            float pv[4];
#pragma unroll
            for (int reg = 0; reg < 4; ++reg) {
                float g2 = cb * cOff[mt][reg] - sb * sOff[mt][reg];
                float arg = fmaf(s_acc[mt][reg], g2, -SM_M * L2E);
                if (diag && (mt * 16 + quad * 4 + reg) > t_l) arg = -1e30f;
                pv[reg] = exp2f(arg);
            }
            lsum += (pv[0] + pv[1]) + (pv[2] + pv[3]);
            uint2 pk = {pack2bf_fast(pv[0], pv[1]), pack2bf_fast(pv[2], pv[3])};
            int slot = ((mt * 2 + (quad >> 1)) ^ (c & 7));
            *(uint2*)&Ps[wave][c * 64 + slot * 8 + (quad & 1) * 4] = pk;
        }

        // advance base angle by one tile (4 ops)
        float ncb = cb * cD - sb * sD;
        sb = sb * cD + cb * sD;
        cb = ncb;
    };

    stageK(0);
    const int jtEnd = 31 - p;                   // tx=1 end >= tx=0 end
    for (int jt = 0; jt <= jtEnd; ++jt) {
        __syncthreads();
        if (jt < jtEnd) stageK(jt + 1);
        stageV(jt);

        const bool doS  = (jt <= qx);
        const bool doPV = (jt >= 1) & (jt <= qx + 1);
        if (doS & doPV) {
            // fused path: PV(jt-1) is independent of S(jt)/softmax(jt);
            // Ps reads precede Ps writes (per-wave in-order LDS -> safe).
            do_pv(jt - 1);
            do_s(jt);
        } else if (doS) {          // jt == 0
            do_s(jt);
        } else if (doPV) {         // jt == qx + 1 (tail of early q-tile)
            do_pv(jt - 1);
        }
    }

    // drain: last tile's PV for the group whose qx == jtEnd (tx=1).
    __syncthreads();
    if (qx == jtEnd) do_pv(jtEnd);

    // epilogue: reduce l across quads, distribute 1/l to rows, write bf16
    float l = lsum;
    l += __shfl_xor(l, 16);
    l += __shfl_xor(l, 32);
    float il = 1.f / l;
    float ilr[4];
#pragma unroll
    for (int reg = 0; reg < 4; ++reg)
        ilr[reg] = __shfl(il, quad * 4 + reg);
#pragma unroll
    for (int reg = 0; reg < 4; ++reg) {
        int t_g = q0 + wq * 16 + quad * 4 + reg;
#pragma unroll
        for (int nt = 0; nt < 4; ++nt)
            att[(size_t)(b * Tc + t_g) * Cc + h * Dc + nt * 16 + c] =
                f2bf(oacc[nt][reg] * ilr[reg]);
    }
}

// ---------------------------------------------------------------------------
extern "C" void kernel_launch(void* const* d_in, const int* in_sizes, int n_in,
                              void* d_out, int out_size, void* d_ws, size_t ws_size,
                              hipStream_t stream)
{
    const float* x     = (const float*)d_in[0];
    const float* Wq    = (const float*)d_in[1];
    const float* Wk    = (const float*)d_in[2];
    const float* Wv    = (const float*)d_in[3];
    const float* Wo    = (const float*)d_in[4];
    const float* theta = (const float*)d_in[5];
    float* out = (float*)d_out;

    const int M = Bc * Tc;                 // 4096
    char* ws = (char*)d_ws;
    const size_t MB = 1 << 20;
    short* xb   = (short*)(ws);             // [0,8)   x bf16
    short* Bqk  = (short*)(ws + 8 * MB);    // [8,16)  permuted [Wq'|Wk']^T bf16
    short* Wvt  = (short*)(ws + 16 * MB);   // [16,18)
    short* Wot  = (short*)(ws + 18 * MB);   // [18,20)
    short* v2t  = (short*)(ws + 28 * MB);   // [28,36) bf16 (B,H,D,T)
    short* attb = (short*)(ws + 36 * MB);   // [36,44)
    short* q2   = (short*)(ws + 44 * MB);   // [44,60) bf16 (B,H,T,128)
    short* k2   = (short*)d_out;            // 16 MB   bf16 (B,H,T,128) until final gemm

    xconv<<<(size_t)M * Cc / 1024, 256, 0, stream>>>(x, xb);
    wtrans_qk<<<dim3(2048 / 64, Cc / 64, 2), 256, 0, stream>>>(Wq, Wk, Bqk);
    wtrans2<<<dim3(Cc / 64, Cc / 64, 2), 256, 0, stream>>>(Wv, Wo, Wvt);

    // fused QK projection + moire transform (writes q2, k2 directly)
    gemm_bt_mfma<2><<<dim3(4096 / 128, M / 128), 256, 0, stream>>>(
        xb, Bqk, nullptr, q2, k2, M, 4096, Cc);
    // fused V projection + head-transpose (writes v2t directly)
    gemm_v2t<<<dim3(Cc / 128, M / 128), 256, 0, stream>>>(xb, Wvt, v2t);

    moire_attn6<<<dim3(16, Hc, Bc), 512, 0, stream>>>(q2, k2, v2t, theta, attb);

    gemm_bt_mfma<0><<<dim3(Cc / 128, M / 128), 256, 0, stream>>>(
        attb, Wot, out, nullptr, nullptr, M, Cc, Cc);
}

// Round 2
// 245.910 us; speedup vs baseline: 1.0761x; 1.0664x over previous
//
#include <hip/hip_runtime.h>
#include <hip/hip_bf16.h>
#include <math.h>

// Problem constants
#define Bc 2
#define Tc 2048
#define Cc 1024
#define Hc 16
#define Dc 64
// SCALE = 1/8, GAMMA = 8

typedef __attribute__((ext_vector_type(8))) short short8;   // 8 bf16 (4 VGPRs)
typedef __attribute__((ext_vector_type(4))) float f32x4;    // MFMA C/D frag

#define L2E 1.44269504088896f
#define SM_M 20.0f   // fixed softmax shift; |scores| << 20 (std ~0.3)

__device__ __forceinline__ short f2bf(float x) {
    unsigned u = __float_as_uint(x);
    u += 0x7fff + ((u >> 16) & 1);      // RNE
    return (short)(u >> 16);
}
// pack two non-negative floats to bf16 pair (round-half-up) in 3 VALU ops
__device__ __forceinline__ unsigned pack2bf_fast(float a, float b) {
    unsigned ua = __float_as_uint(a) + 0x8000u;
    unsigned ub = __float_as_uint(b) + 0x8000u;
    return __builtin_amdgcn_perm(ub, ua, 0x07060302);  // (ua>>16)|(ub&0xffff0000)
}
// fast softplus: 2 HW transcendentals, ~1e-6 rel err (invisible at bf16)
__device__ __forceinline__ float softplus_fast(float a) {
    return fmaxf(a, 0.f) + __logf(1.f + __expf(-fabsf(a)));
}

// ---------------------------------------------------------------------------
// 256x256 8-phase bf16 GEMM with fused moire-QK epilogue (m201 template).
// C[M=4096, N=4096] = xb[4096,1024] @ Bqk[4096,1024]^T, K-tiles of 64.
// 8 waves (2M x 4N), per-wave C = 128x64 split in 4 quadrants of 64x32.
// Per phase: {ds_read subtile || stage 1 half-tile via global_load_lds} ->
// s_barrier -> setprio(1) 16 MFMA setprio(0) -> [vmcnt(6) @ p4/p8] -> barrier.
// LDS: A,B each [2 dbuf][2 half][128x64] = 128 KB total. XOR swizzle
// (row&7)<<4 applied on BOTH the pre-swizzled global source of
// global_load_lds and the ds_read offset (rule #21) -> conflict-free b128.
// Stage stream per group g_t (tile t+2): Bh0@p2, Ah0@p3, Bh1@p4, Ah1@p+1;
// verified: every half staged after its last read (WAR-safe across the
// phase barrier) and landed before its first read under vmcnt(6) at p4/p8.
// Last iteration (no more prefetch) waits vmcnt(0) to cover the tail.
// Raw s_barrier (asm, "memory") -- __syncthreads would drain vmcnt(0) and
// destroy the counted-vmcnt pipeline.
// Epilogue: needs the wtrans_qk permutation j=(d>>4)*32+sub*16+(d&15) so
// amp (nf=0) and phase (nf=1) for d = wn*16+c are in the SAME lane; q2/k2
// stores stay 16-lane-contiguous 32B runs (R5 write-amplification rule).
// ---------------------------------------------------------------------------
#define RDA(BUF, MH) do {                                                      \
    const short* Ah_ = &Al[BUF][MH][0];                                        \
    _Pragma("unroll") for (int mt_ = 0; mt_ < 4; ++mt_) {                      \
        af[mt_][0] = *(const short8*)&Ah_[(wm*64 + mt_*16 + c)*64 + rsw0];     \
        af[mt_][1] = *(const short8*)&Ah_[(wm*64 + mt_*16 + c)*64 + rsw1];     \
    } } while (0)

#define RDB(BUF, NH) do {                                                      \
    const short* Bh_ = &Bl[BUF][NH][0];                                        \
    _Pragma("unroll") for (int nf_ = 0; nf_ < 2; ++nf_) {                      \
        bfr[NH][nf_][0] = *(const short8*)&Bh_[(wn*32 + nf_*16 + c)*64 + rsw0];\
        bfr[NH][nf_][1] = *(const short8*)&Bh_[(wn*32 + nf_*16 + c)*64 + rsw1];\
    } } while (0)

#define MMQ(MH, NH) do {                                                       \
    _Pragma("unroll") for (int mt_ = 0; mt_ < 4; ++mt_)                        \
    _Pragma("unroll") for (int nf_ = 0; nf_ < 2; ++nf_) {                      \
        acc[MH][NH][mt_][nf_] = __builtin_amdgcn_mfma_f32_16x16x32_bf16(       \
            af[mt_][0], bfr[NH][nf_][0], acc[MH][NH][mt_][nf_], 0, 0, 0);      \
        acc[MH][NH][mt_][nf_] = __builtin_amdgcn_mfma_f32_16x16x32_bf16(       \
            af[mt_][1], bfr[NH][nf_][1], acc[MH][NH][mt_][nf_], 0, 0, 0);      \
    } } while (0)

#define BARw asm volatile("s_barrier" ::: "memory")
#define VMW6 asm volatile("s_waitcnt vmcnt(6)" ::: "memory")
#define VMW0 asm volatile("s_waitcnt vmcnt(0)" ::: "memory")
#define PRIO1 __builtin_amdgcn_s_setprio(1)
#define PRIO0 __builtin_amdgcn_s_setprio(0)

__global__ __launch_bounds__(512, 2) void gemm256_qk(
    const short* __restrict__ A, const short* __restrict__ Bt,
    short* __restrict__ q2, short* __restrict__ k2)
{
    __shared__ __attribute__((aligned(16))) short Al[2][2][128 * 64];  // 64 KB
    __shared__ __attribute__((aligned(16))) short Bl[2][2][128 * 64];  // 64 KB

    const int tid = threadIdx.x;
    const int wave = tid >> 6, lane = tid & 63;
    const int quad = lane >> 4, c = lane & 15;
    const int wm = wave >> 2, wn = wave & 3;          // 2M x 4N waves
    const int m0 = blockIdx.y * 256, n0 = blockIdx.x * 256;

    // swizzled ds_read byte-slot (shorts): (ks*64 + quad*16) ^ ((c&7)<<4)
    const int rsw0 = ((quad * 16) ^ ((c & 7) << 4)) >> 1;
    const int rsw1 = ((64 + quad * 16) ^ ((c & 7) << 4)) >> 1;

    f32x4 acc[2][2][4][2];
#pragma unroll
    for (int a0 = 0; a0 < 2; ++a0)
#pragma unroll
        for (int a1 = 0; a1 < 2; ++a1)
#pragma unroll
            for (int a2 = 0; a2 < 4; ++a2)
#pragma unroll
                for (int a3 = 0; a3 < 2; ++a3)
                    acc[a0][a1][a2][a3] = (f32x4){0.f, 0.f, 0.f, 0.f};

    short8 af[4][2];        // A-frags: 4 m-frags x 2 k-steps (32 VGPR)
    short8 bfr[2][2][2];    // B-frags: [nh][nf][ks] both halves kept (32 VGPR)

    // stage one 128x64 half-tile (16 KB): 2 x global_load_lds(16B)/thread.
    // LDS dest linear; global source pre-swizzled by ((row&7)<<4) bytes.
    auto stA = [&](int kt, int hh) {
        short* dstb = &Al[kt & 1][hh][0];
#pragma unroll
        for (int j = 0; j < 2; ++j) {
            int ch = j * 512 + tid;
            int row = ch >> 3;
            int os = ((((ch & 7) << 4) ^ ((row & 7) << 4)) >> 1);
            const short* src = A + (size_t)(m0 + hh * 128 + row) * 1024 + kt * 64 + os;
            __builtin_amdgcn_global_load_lds(
                (const __attribute__((address_space(1))) void*)src,
                (__attribute__((address_space(3))) void*)(dstb + (j * 512 + wave * 64) * 8),
                16, 0, 0);
        }
    };
    auto stB = [&](int kt, int hh) {
        short* dstb = &Bl[kt & 1][hh][0];
#pragma unroll
        for (int j = 0; j < 2; ++j) {
            int ch = j * 512 + tid;
            int row = ch >> 3;
            int os = ((((ch & 7) << 4) ^ ((row & 7) << 4)) >> 1);
            const short* src = Bt + (size_t)(n0 + hh * 128 + row) * 1024 + kt * 64 + os;
            __builtin_amdgcn_global_load_lds(
                (const __attribute__((address_space(1))) void*)src,
                (__attribute__((address_space(3))) void*)(dstb + (j * 512 + wave * 64) * 8),
                16, 0, 0);
        }
    };

    // prologue: tile0 fully + tile1 {Bh0, Ah0, Bh1}; Ah1(1) comes at p1 of i=0.
    stB(0, 0); stA(0, 0); stB(0, 1); stA(0, 1); stB(1, 0); stA(1, 0); stB(1, 1);
    VMW6;          // oldest 8 loads (= all of tile 0) landed
    BARw;

    // K = 1024 -> 16 K-tiles -> 8 iterations of 2 tiles (buf0 = even tile).
    for (int i = 0; i < 8; ++i) {
        const int e = 2 * i;
        const bool more = (i < 7);
        // ---- group e (buf 0) ----
        RDA(0, 0); RDB(0, 0);                 // p1: 12 ds_reads
        stA(e + 1, 1);                        //     stage Ah1(odd tile)
        BARw; PRIO1; MMQ(0, 0); PRIO0; BARw;
        RDB(0, 1);                            // p2: 4 ds_reads (A kept)
        if (more) stB(e + 2, 0);
        BARw; PRIO1; MMQ(0, 1); PRIO0; BARw;
        RDA(0, 1);                            // p3: 8 ds_reads (B0 kept)
        if (more) stA(e + 2, 0);
        BARw; PRIO1; MMQ(1, 0); PRIO0; BARw;
        if (more) stB(e + 2, 1);              // p4: no ds_reads (A,B1 kept)
        BARw; PRIO1; MMQ(1, 1); PRIO0;
        if (more) { VMW6; } else { VMW0; }
        BARw;
        // ---- group o (buf 1) ----
        RDA(1, 0); RDB(1, 0);                 // p5
        if (more) stA(e + 2, 1);
        BARw; PRIO1; MMQ(0, 0); PRIO0; BARw;
        RDB(1, 1);                            // p6
        if (more) stB(e + 3, 0);
        BARw; PRIO1; MMQ(0, 1); PRIO0; BARw;
        RDA(1, 1);                            // p7
        if (more) stA(e + 3, 0);
        BARw; PRIO1; MMQ(1, 0); PRIO0; BARw;
        if (more) stB(e + 3, 1);              // p8
        BARw; PRIO1; MMQ(1, 1); PRIO0;
        if (more) { VMW6; } else { VMW0; }
        BARw;
    }

    // moire epilogue: cols of this lane: n = n0 + nh*128 + wn*32 + nf*16 + c
    // -> group g = 2*bx + nh, amp at nf=0, phase at nf=1, d = wn*16 + c.
    const int bx = blockIdx.x;
    const int d = wn * 16 + c;
#pragma unroll
    for (int mh = 0; mh < 2; ++mh) {
#pragma unroll
        for (int nh = 0; nh < 2; ++nh) {
            const int g = 2 * bx + nh;
            const int isK = g >> 4;
            const int hh = g & 15;
            const float scl = isK ? 1.f : 0.125f;
            short* dst = isK ? k2 : q2;       // (B,H,T,128)
#pragma unroll
            for (int mt = 0; mt < 4; ++mt) {
#pragma unroll
                for (int reg = 0; reg < 4; ++reg) {
                    int m = m0 + mh * 128 + wm * 64 + mt * 16 + quad * 4 + reg;
                    int bb = m >> 11, tt = m & (Tc - 1);
                    size_t base = (((size_t)bb * Hc + hh) * Tc + tt) * 128;
                    float amp = acc[mh][nh][mt][0][reg];
                    float ph  = acc[mh][nh][mt][1][reg];
                    float sp = softplus_fast(amp) * scl;
                    float sn, cs;
                    __sincosf(ph, &sn, &cs);
                    dst[base + d]      = f2bf(sp * cs);
                    dst[base + d + 64] = f2bf(sp * sn);
                }
            }
        }
    }
}

// ---------------------------------------------------------------------------
// bf16 MFMA GEMM (m97 recipe): C[M,N] = A[M,K] @ Bt[N,K]^T  (EPI 0: f32 out)
// Still used for the final Wo projection (N=1024 -> 256-block grid; the
// 256^2 template would leave 3/4 of the CUs idle there).
// ---------------------------------------------------------------------------
template <int EPI>
__global__ __launch_bounds__(256) void gemm_bt_mfma(
    const short* __restrict__ A, const short* __restrict__ Bt,
    float* __restrict__ Cf, short* __restrict__ Cb,
    int M, int N, int K)
{
    __shared__ __attribute__((aligned(16))) short As[128 * 32];
    __shared__ __attribute__((aligned(16))) short Bs[128 * 32];

    const int tid = threadIdx.x;
    const int wave = tid >> 6, lane = tid & 63;
    const int quad = lane >> 4, c = lane & 15;
    const int wm = wave >> 1, wn = wave & 1;
    const int m0 = blockIdx.y * 128, n0 = blockIdx.x * 128;

    const int srow = lane >> 2;
    const int scol = (lane & 3) * 8;
    const short* Ag = A  + (size_t)(m0 + wave * 32 + srow) * K + scol;
    const short* Bg = Bt + (size_t)(n0 + wave * 32 + srow) * K + scol;
    short* AsW = As + (wave * 32) * 32;
    short* BsW = Bs + (wave * 32) * 32;

    f32x4 acc[4][4];
#pragma unroll
    for (int i = 0; i < 4; ++i)
#pragma unroll
        for (int j = 0; j < 4; ++j)
            acc[i][j] = (f32x4){0.f, 0.f, 0.f, 0.f};

    for (int k0 = 0; k0 < K; k0 += 32) {
        __syncthreads();
#pragma unroll
        for (int i = 0; i < 2; ++i) {
            __builtin_amdgcn_global_load_lds(
                (const __attribute__((address_space(1))) void*)(Ag + k0 + (size_t)i * 16 * K),
                (__attribute__((address_space(3))) void*)(AsW + i * 16 * 32), 16, 0, 0);
            __builtin_amdgcn_global_load_lds(
                (const __attribute__((address_space(1))) void*)(Bg + k0 + (size_t)i * 16 * K),
                (__attribute__((address_space(3))) void*)(BsW + i * 16 * 32), 16, 0, 0);
        }
        __syncthreads();

        short8 af[4], bf[4];
#pragma unroll
        for (int mt = 0; mt < 4; ++mt)
            af[mt] = *(const short8*)&As[(wm * 64 + mt * 16 + c) * 32 + quad * 8];
#pragma unroll
        for (int nt = 0; nt < 4; ++nt)
            bf[nt] = *(const short8*)&Bs[(wn * 64 + nt * 16 + c) * 32 + quad * 8];
#pragma unroll
        for (int mt = 0; mt < 4; ++mt)
#pragma unroll
            for (int nt = 0; nt < 4; ++nt)
                acc[mt][nt] = __builtin_amdgcn_mfma_f32_16x16x32_bf16(
                    af[mt], bf[nt], acc[mt][nt], 0, 0, 0);
    }

#pragma unroll
    for (int mt = 0; mt < 4; ++mt) {
#pragma unroll
        for (int reg = 0; reg < 4; ++reg) {
            size_t row = m0 + wm * 64 + mt * 16 + quad * 4 + reg;
#pragma unroll
            for (int nt = 0; nt < 4; ++nt) {
                size_t col = n0 + wn * 64 + nt * 16 + c;
                if (EPI == 1) Cb[row * N + col] = f2bf(acc[mt][nt][reg]);
                else          Cf[row * N + col] = acc[mt][nt][reg];
            }
        }
    }
}

// ---------------------------------------------------------------------------
// V projection fused with head-transpose: v2t[(b,h,d),t] = (xb @ Wvt^T).
// ---------------------------------------------------------------------------
__global__ __launch_bounds__(256) void gemm_v2t(
    const short* __restrict__ A, const short* __restrict__ Bt,
    short* __restrict__ v2t)
{
    __shared__ __attribute__((aligned(16))) short As[128 * 32];
    __shared__ __attribute__((aligned(16))) short Bs[128 * 32];
    __shared__ __attribute__((aligned(16))) short tile[128 * 136];  // [n][t]

    const int K = Cc;
    const int tid = threadIdx.x;
    const int wave = tid >> 6, lane = tid & 63;
    const int quad = lane >> 4, c = lane & 15;
    const int wm = wave >> 1, wn = wave & 1;
    const int m0 = blockIdx.y * 128, n0 = blockIdx.x * 128;

    const int srow = lane >> 2;
    const int scol = (lane & 3) * 8;
    const short* Ag = A  + (size_t)(m0 + wave * 32 + srow) * K + scol;
    const short* Bg = Bt + (size_t)(n0 + wave * 32 + srow) * K + scol;
    short* AsW = As + (wave * 32) * 32;
    short* BsW = Bs + (wave * 32) * 32;

    f32x4 acc[4][4];
#pragma unroll
    for (int i = 0; i < 4; ++i)
#pragma unroll
        for (int j = 0; j < 4; ++j)
            acc[i][j] = (f32x4){0.f, 0.f, 0.f, 0.f};

    for (int k0 = 0; k0 < K; k0 += 32) {
        __syncthreads();
#pragma unroll
        for (int i = 0; i < 2; ++i) {
            __builtin_amdgcn_global_load_lds(
                (const __attribute__((address_space(1))) void*)(Ag + k0 + (size_t)i * 16 * K),
                (__attribute__((address_space(3))) void*)(AsW + i * 16 * 32), 16, 0, 0);
            __builtin_amdgcn_global_load_lds(
                (const __attribute__((address_space(1))) void*)(Bg + k0 + (size_t)i * 16 * K),
                (__attribute__((address_space(3))) void*)(BsW + i * 16 * 32), 16, 0, 0);
        }
        __syncthreads();

        short8 af[4], bf[4];
#pragma unroll
        for (int mt = 0; mt < 4; ++mt)
            af[mt] = *(const short8*)&As[(wm * 64 + mt * 16 + c) * 32 + quad * 8];
#pragma unroll
        for (int nt = 0; nt < 4; ++nt)
            bf[nt] = *(const short8*)&Bs[(wn * 64 + nt * 16 + c) * 32 + quad * 8];
#pragma unroll
        for (int mt = 0; mt < 4; ++mt)
#pragma unroll
            for (int nt = 0; nt < 4; ++nt)
                acc[mt][nt] = __builtin_amdgcn_mfma_f32_16x16x32_bf16(
                    af[mt], bf[nt], acc[mt][nt], 0, 0, 0);
    }

    // epilogue: stash transposed into LDS [n][t]
#pragma unroll
    for (int mt = 0; mt < 4; ++mt)
#pragma unroll
        for (int reg = 0; reg < 4; ++reg) {
            int tl = wm * 64 + mt * 16 + quad * 4 + reg;
#pragma unroll
            for (int nt = 0; nt < 4; ++nt)
                tile[(wn * 64 + nt * 16 + c) * 136 + tl] = f2bf(acc[mt][nt][reg]);
        }
    __syncthreads();

    const int b = m0 >> 11, tl0 = m0 & (Tc - 1);
#pragma unroll
    for (int i = 0; i < 8; ++i) {
        int n = i * 16 + (tid >> 4);
        int t8 = (tid & 15) * 8;
        int ng = n0 + n, h = ng >> 6, d = ng & 63;
        *(short8*)&v2t[(((size_t)b * Hc + h) * Dc + d) * Tc + tl0 + t8] =
            *(const short8*)&tile[n * 136 + t8];
    }
}

// ---------------------------------------------------------------------------
__global__ __launch_bounds__(256) void xconv(const float* __restrict__ x,
                                             short* __restrict__ xb)
{
    int idx = blockIdx.x * 256 + threadIdx.x;
    float4 v = *(const float4*)&x[(size_t)idx * 4];
    short4 o = {f2bf(v.x), f2bf(v.y), f2bf(v.z), f2bf(v.w)};
    *(short4*)&xb[(size_t)idx * 4] = o;
}

// ---------------------------------------------------------------------------
// Wq|Wk transpose-convert with the gemm256_qk row permutation.
// Source col ng (0..2047) of half z: sub = ng>>10 (amp/ph), h = (ng>>6)&15,
// d = ng&63. Dest row r = (z*16+h)*128 + (d>>4)*32 + sub*16 + (d&15), so in
// the 256^2 wave layout (j = wn*32 + nf*16 + c) amp lands at nf=0 and its
// matching phase at nf=1 in the SAME lane, d = wn*16 + c.
// ---------------------------------------------------------------------------
__global__ __launch_bounds__(256) void wtrans_qk(const float* __restrict__ Wq,
                                                 const float* __restrict__ Wk,
                                                 short* __restrict__ Bt)
{
    __shared__ short tile[64][80];
    const int n0 = blockIdx.x * 64, k0 = blockIdx.y * 64;
    const int half = blockIdx.z;
    const float* W = half ? Wk : Wq;
    const int tid = threadIdx.x;
#pragma unroll
    for (int i = 0; i < 4; ++i) {
        int e = i * 256 + tid;
        int k = e >> 4, n4 = (e & 15) * 4;
        float4 v = *(const float4*)&W[(size_t)(k0 + k) * 2048 + n0 + n4];
        tile[k][n4]     = f2bf(v.x);
        tile[k][n4 + 1] = f2bf(v.y);
        tile[k][n4 + 2] = f2bf(v.z);
        tile[k][n4 + 3] = f2bf(v.w);
    }
    __syncthreads();
#pragma unroll
    for (int i = 0; i < 16; ++i) {
        int e = i * 256 + tid;
        int n = e >> 6, k = e & 63;
        int ng = n0 + n;
        int sub = ng >> 10, hh = (ng >> 6) & 15, dd = ng & 63;
        int r = (half * 16 + hh) * 128 + (dd >> 4) * 32 + sub * 16 + (dd & 15);
        Bt[(size_t)r * Cc + k0 + k] = tile[k][n];
    }
}

// ---------------------------------------------------------------------------
__global__ __launch_bounds__(256) void wtrans2(const float* __restrict__ Wv,
                                               const float* __restrict__ Wo,
                                               short* __restrict__ WtBase)
{
    __shared__ short tile[64][80];
    const int n0 = blockIdx.x * 64, k0 = blockIdx.y * 64;
    const float* W = blockIdx.z ? Wo : Wv;
    short* Wt = WtBase + (size_t)blockIdx.z * Cc * Cc;
    const int tid = threadIdx.x;
#pragma unroll
    for (int i = 0; i < 4; ++i) {
        int e = i * 256 + tid;
        int k = e >> 4, n4 = (e & 15) * 4;
        float4 v = *(const float4*)&W[(size_t)(k0 + k) * Cc + n0 + n4];
        tile[k][n4]     = f2bf(v.x);
        tile[k][n4 + 1] = f2bf(v.y);
        tile[k][n4 + 2] = f2bf(v.z);
        tile[k][n4 + 3] = f2bf(v.w);
    }
    __syncthreads();
#pragma unroll
    for (int i = 0; i < 16; ++i) {
        int e = i * 256 + tid;
        int n = e >> 6, k = e & 63;
        Wt[(size_t)(n0 + n) * Cc + k0 + k] = tile[k][n];
    }
}

// ---------------------------------------------------------------------------
// MFMA flash attention v6: one-tile-deep software pipeline (unchanged).
// ---------------------------------------------------------------------------
__global__ __launch_bounds__(512, 4) void moire_attn6(
    const short* __restrict__ q2, const short* __restrict__ k2,
    const short* __restrict__ v2t, const float* __restrict__ theta,
    short* __restrict__ att)
{
    __shared__ __attribute__((aligned(16))) short Ks[2][64 * 128];  // 32 KB
    __shared__ __attribute__((aligned(16))) short Vt[2][64 * 64];   // 16 KB
    __shared__ __attribute__((aligned(16))) short Ps[8][16 * 64];   // 16 KB

    const int tid = threadIdx.x;
    const int wave = tid >> 6, lane = tid & 63;
    const int quad = lane >> 4, c = lane & 15;
    const int tx = wave >> 2, wq = wave & 3;
    const int p = blockIdx.x, h = blockIdx.y, b = blockIdx.z;
    const int qx = tx ? (31 - p) : p;    // this wave's q-tile
    const int q0 = qx * 64;
    const float th = theta[h];

    const short* k2b = k2 + (size_t)(b * Hc + h) * Tc * 128;
    const short* v2b = v2t + (size_t)(b * Hc + h) * Dc * Tc;

    // Q B-frags (n = t): row q0 + wq*16 + c, 4 K-chunks of 32
    short8 qf[4];
    const short* qp = q2 + ((size_t)(b * Hc + h) * Tc + q0 + wq * 16 + c) * 128;
#pragma unroll
    for (int i = 0; i < 4; ++i)
        qf[i] = *(const short8*)(qp + i * 32 + quad * 8);

    // gate*L2E = cb*cOff - sb*sOff, base (cb,sb) = angle th/8*(jt*64 - q0 - t_l)
    const int t_l = wq * 16 + c;
    float x0 = th * 0.125f * (float)(q0 + t_l);
    float cb = __cosf(x0), sb = -__sinf(x0);
    float cOff[4][4], sOff[4][4];
#pragma unroll
    for (int mt = 0; mt < 4; ++mt)
#pragma unroll
        for (int reg = 0; reg < 4; ++reg) {
            float a = th * 0.125f * (float)(mt * 16 + quad * 4 + reg);
            cOff[mt][reg] = __cosf(a) * L2E;
            sOff[mt][reg] = __sinf(a) * L2E;
        }
    const float cD = __cosf(8.f * th), sD = __sinf(8.f * th);  // 64-step rotation

    f32x4 oacc[4];
    float lsum = 0.f;
#pragma unroll
    for (int nt = 0; nt < 4; ++nt)
        oacc[nt] = (f32x4){0.f, 0.f, 0.f, 0.f};

    auto stageK = [&](int jts) {
        short* KsB = &Ks[jts & 1][0];
        const int s0 = jts * 64;
#pragma unroll
        for (int i = 0; i < 2; ++i) {          // Ks: 1024 16B chunks
            int ch = i * 512 + tid;
            int row = ch >> 4, j = ch & 15;
            const short* src = k2b + (size_t)(s0 + row) * 128 + ((j ^ (row & 15)) << 3);
            __builtin_amdgcn_global_load_lds(
                (const __attribute__((address_space(1))) void*)src,
                (__attribute__((address_space(3))) void*)(KsB + (i * 512 + wave * 64) * 8),
                16, 0, 0);
        }
    };
    auto stageV = [&](int jts) {
        short* VtB = &Vt[jts & 1][0];
        const int s0 = jts * 64;
        int row = tid >> 3, j = tid & 7;       // Vt: 512 16B chunks
        const short* src = v2b + (size_t)row * Tc + s0 + ((j ^ (row & 7)) << 3);
        __builtin_amdgcn_global_load_lds(
            (const __attribute__((address_space(1))) void*)src,
            (__attribute__((address_space(3))) void*)(VtB + (wave * 64) * 8),
            16, 0, 0);
    };

    auto do_pv = [&](int jprev) {
        const short* VtB = &Vt[jprev & 1][0];
        short8 pf[2];
#pragma unroll
        for (int kk = 0; kk < 2; ++kk)
            pf[kk] = *(const short8*)&Ps[wave][c * 64 +
                         (((kk * 4 + quad) ^ (c & 7)) << 3)];
#pragma unroll
        for (int nt = 0; nt < 4; ++nt)
#pragma unroll
            for (int kk = 0; kk < 2; ++kk) {
                short8 vf = *(const short8*)&VtB[(nt * 16 + c) * 64 +
                             (((kk * 4 + quad) ^ (c & 7)) << 3)];
                oacc[nt] = __builtin_amdgcn_mfma_f32_16x16x32_bf16(
                    pf[kk], vf, oacc[nt], 0, 0, 0);
            }
    };

    auto do_s = [&](int jt) {
        const short* KsB = &Ks[jt & 1][0];
        const bool diag = (jt == qx);

        // S^T = K Q^T : kf A-operand (m=s), qf B-operand (n=t)
        f32x4 s_acc[4];
#pragma unroll
        for (int mt = 0; mt < 4; ++mt) {
            f32x4 a = {0.f, 0.f, 0.f, 0.f};
#pragma unroll
            for (int kk = 0; kk < 4; ++kk) {
                short8 kf = *(const short8*)&KsB[(mt * 16 + c) * 128 +
                                                 (((kk * 4 + quad) ^ c) << 3)];
                a = __builtin_amdgcn_mfma_f32_16x16x32_bf16(kf, qf[kk], a, 0, 0, 0);
            }
            s_acc[mt] = a;
        }

        // p = exp2(s*gate*L2E - M*L2E); fixed shift M (exact softmax)
#pragma unroll
        for (int mt = 0; mt < 4; ++mt) {
            float pv[4];
#pragma unroll
            for (int reg = 0; reg < 4; ++reg) {
                float g2 = cb * cOff[mt][reg] - sb * sOff[mt][reg];
                float arg = fmaf(s_acc[mt][reg], g2, -SM_M * L2E);
                if (diag && (mt * 16 + quad * 4 + reg) > t_l) arg = -1e30f;
                pv[reg] = exp2f(arg);
            }
            lsum += (pv[0] + pv[1]) + (pv[2] + pv[3]);
            uint2 pk = {pack2bf_fast(pv[0], pv[1]), pack2bf_fast(pv[2], pv[3])};
            int slot = ((mt * 2 + (quad >> 1)) ^ (c & 7));
            *(uint2*)&Ps[wave][c * 64 + slot * 8 + (quad & 1) * 4] = pk;
        }

        // advance base angle by one tile (4 ops)
        float ncb = cb * cD - sb * sD;
        sb = sb * cD + cb * sD;
        cb = ncb;
    };

    stageK(0);
    const int jtEnd = 31 - p;                   // tx=1 end >= tx=0 end
    for (int jt = 0; jt <= jtEnd; ++jt) {
        __syncthreads();
        if (jt < jtEnd) stageK(jt + 1);
        stageV(jt);

        const bool doS  = (jt <= qx);
        const bool doPV = (jt >= 1) & (jt <= qx + 1);
        if (doS & doPV) {
            do_pv(jt - 1);
            do_s(jt);
        } else if (doS) {          // jt == 0
            do_s(jt);
        } else if (doPV) {         // jt == qx + 1 (tail of early q-tile)
            do_pv(jt - 1);
        }
    }

    // drain: last tile's PV for the group whose qx == jtEnd (tx=1).
    __syncthreads();
    if (qx == jtEnd) do_pv(jtEnd);

    // epilogue: reduce l across quads, distribute 1/l to rows, write bf16
    float l = lsum;
    l += __shfl_xor(l, 16);
    l += __shfl_xor(l, 32);
    float il = 1.f / l;
    float ilr[4];
#pragma unroll
    for (int reg = 0; reg < 4; ++reg)
        ilr[reg] = __shfl(il, quad * 4 + reg);
#pragma unroll
    for (int reg = 0; reg < 4; ++reg) {
        int t_g = q0 + wq * 16 + quad * 4 + reg;
#pragma unroll
        for (int nt = 0; nt < 4; ++nt)
            att[(size_t)(b * Tc + t_g) * Cc + h * Dc + nt * 16 + c] =
                f2bf(oacc[nt][reg] * ilr[reg]);
    }
}

// ---------------------------------------------------------------------------
extern "C" void kernel_launch(void* const* d_in, const int* in_sizes, int n_in,
                              void* d_out, int out_size, void* d_ws, size_t ws_size,
                              hipStream_t stream)
{
    const float* x     = (const float*)d_in[0];
    const float* Wq    = (const float*)d_in[1];
    const float* Wk    = (const float*)d_in[2];
    const float* Wv    = (const float*)d_in[3];
    const float* Wo    = (const float*)d_in[4];
    const float* theta = (const float*)d_in[5];
    float* out = (float*)d_out;

    const int M = Bc * Tc;                 // 4096
    char* ws = (char*)d_ws;
    const size_t MB = 1 << 20;
    short* xb   = (short*)(ws);             // [0,8)   x bf16
    short* Bqk  = (short*)(ws + 8 * MB);    // [8,16)  permuted [Wq'|Wk']^T bf16
    short* Wvt  = (short*)(ws + 16 * MB);   // [16,18)
    short* Wot  = (short*)(ws + 18 * MB);   // [18,20)
    short* v2t  = (short*)(ws + 28 * MB);   // [28,36) bf16 (B,H,D,T)
    short* attb = (short*)(ws + 36 * MB);   // [36,44)
    short* q2   = (short*)(ws + 44 * MB);   // [44,60) bf16 (B,H,T,128)
    short* k2   = (short*)d_out;            // 16 MB   bf16 (B,H,T,128) until final gemm

    xconv<<<(size_t)M * Cc / 1024, 256, 0, stream>>>(x, xb);
    wtrans_qk<<<dim3(2048 / 64, Cc / 64, 2), 256, 0, stream>>>(Wq, Wk, Bqk);
    wtrans2<<<dim3(Cc / 64, Cc / 64, 2), 256, 0, stream>>>(Wv, Wo, Wvt);

    // fused QK projection + moire transform (256^2 8-phase, writes q2, k2)
    gemm256_qk<<<dim3(4096 / 256, M / 256), 512, 0, stream>>>(xb, Bqk, q2, k2);
    // fused V projection + head-transpose (writes v2t directly)
    gemm_v2t<<<dim3(Cc / 128, M / 128), 256, 0, stream>>>(xb, Wvt, v2t);

    moire_attn6<<<dim3(16, Hc, Bc), 512, 0, stream>>>(q2, k2, v2t, theta, attb);

    gemm_bt_mfma<0><<<dim3(Cc / 128, M / 128), 256, 0, stream>>>(
        attb, Wot, out, nullptr, M, Cc, Cc);
}